// Round 2
// baseline (3837.880 us; speedup 1.0000x reference)
//
#include <hip/hip_runtime.h>
#include <math.h>

// Problem constants
#define NB 16
#define NPT 4096
#define KNN 20
#define CNT_INV (1.0f / 1310720.0f)   // 1 / (B*N*K)

// ---------------------------------------------------------------------------
// KNN: one wave (64 lanes) per point. Distances for all 4096 candidates
// computed in FLOAT64 (the harness's np reference computes top-k on f64
// distances; f32 op-order differences flip rank-20 near-ties), stored in LDS,
// then 20 rounds of wave-argmax (tie-break: lowest index).
// ---------------------------------------------------------------------------
__global__ __launch_bounds__(64) void knn_kernel(const float* __restrict__ x,
                                                 int* __restrict__ idx_out) {
  __shared__ double d[4096];
  const int p = blockIdx.x;            // 0..65535
  const int b = p >> 12, n = p & 4095;
  const int lane = threadIdx.x;
  const float* xb = x + (size_t)b * 3 * 4096;
  const double cx0 = (double)xb[n];
  const double cx1 = (double)xb[4096 + n];
  const double cx2 = (double)xb[8192 + n];
  const double sqn = cx0 * cx0 + cx1 * cx1 + cx2 * cx2;

  double v = -INFINITY; int vi = 0;
  for (int i = 0; i < 64; ++i) {
    const int m = i * 64 + lane;
    const double y0 = (double)xb[m];
    const double y1 = (double)xb[4096 + m];
    const double y2 = (double)xb[8192 + m];
    const double dot = cx0 * y0 + cx1 * y1 + cx2 * y2;
    const double sqm = y0 * y0 + y1 * y1 + y2 * y2;
    const double nd = (2.0 * dot - sqn) - sqm;   // same formula as reference
    d[m] = nd;
    if (nd > v) { v = nd; vi = m; }              // strict > keeps lowest index
  }
  for (int r = 0; r < KNN; ++r) {
    double bv = v; int bi = vi;
    // butterfly argmax over 64 lanes, tie-break lower index
    for (int off = 1; off < 64; off <<= 1) {
      const double ov = __shfl_xor(bv, off);
      const int oi = __shfl_xor(bi, off);
      if (ov > bv || (ov == bv && oi < bi)) { bv = ov; bi = oi; }
    }
    if (lane == 0) idx_out[p * KNN + r] = bi;
    if ((bi & 63) == lane) {           // owner lane invalidates + rescans
      d[bi] = -INFINITY;
      v = -INFINITY; vi = 0;
      for (int i = 0; i < 64; ++i) {
        const int m = i * 64 + lane;
        const double nd = d[m];
        if (nd > v) { v = nd; vi = m; }
      }
    }
  }
}

// ---------------------------------------------------------------------------
// Stage kernel: one wave per point (lane = channel), 4 waves/block, each wave
// processes exactly 8 points (grid 2048 x 256). BN folded into W2'/W3'
// (transposed [c][o] in global, rows pulled into per-lane registers).
// STAGE=1: stats of l1.  STAGE=2: recompute l1, stats of l2.
// STAGE=3: recompute l1,l2; l3 -> per-point max/min over k + stats of l3.
// ---------------------------------------------------------------------------
template <int STAGE>
__global__ __launch_bounds__(256, 2) void stage_kernel(
    const float* __restrict__ x, const int* __restrict__ nbr,
    const float* __restrict__ W1,
    const float* __restrict__ w2ft, const float* __restrict__ b2f,
    const float* __restrict__ w3ft, const float* __restrict__ b3f,
    float* __restrict__ sumO, float* __restrict__ sqO,
    float* __restrict__ mx, float* __restrict__ mn) {
  extern __shared__ char smem[];
  float* pts  = (float*)smem;                    // [4][64] (21*3 used)  1024 B
  float* W1T  = (float*)(smem + 1024);           // [6][64]              1536 B
  float* lbuf = (float*)(smem + 1024 + 1536);    // [4][20][64]         20480 B
  float* redS = (float*)(smem + 23040);          // [4][64]
  float* redQ = redS + 256;                      // [4][64]   total 25088 B

  const int tid = threadIdx.x;
  const int wave = tid >> 6, lane = tid & 63;

  for (int i = tid; i < 384; i += 256) {
    const int c = i >> 6, o = i & 63;
    W1T[i] = W1[o * 6 + c];
  }
  __syncthreads();

  float w1r[6];
#pragma unroll
  for (int c = 0; c < 6; ++c) w1r[c] = W1T[c * 64 + lane];
  float w2r[64], w3r[64];
  if (STAGE >= 2) {
#pragma unroll
    for (int c = 0; c < 64; ++c) w2r[c] = w2ft[c * 64 + lane];  // coalesced
  }
  if (STAGE == 3) {
#pragma unroll
    for (int c = 0; c < 64; ++c) w3r[c] = w3ft[c * 64 + lane];
  }
  const float bias2 = (STAGE >= 2) ? b2f[lane] : 0.f;
  const float bias3 = (STAGE == 3) ? b3f[lane] : 0.f;

  float ssum = 0.f, ssq = 0.f;
  const int wgid = blockIdx.x * 4 + wave;
  float* lb = lbuf + wave * 1280;
  float* pw = pts + wave * 64;
  const float4* lb4 = (const float4*)lb;

  for (int it = 0; it < 8; ++it) {
    const int p = wgid + it * 8192;
    const int b = p >> 12, n = p & 4095;
    const float* xb = x + (size_t)b * 12288;
    if (lane < KNN) {
      const int kk = nbr[p * KNN + lane];
      pw[lane * 3 + 0] = xb[kk];
      pw[lane * 3 + 1] = xb[4096 + kk];
      pw[lane * 3 + 2] = xb[8192 + kk];
    } else if (lane == KNN) {
      pw[60] = xb[n]; pw[61] = xb[4096 + n]; pw[62] = xb[8192 + n];
    }
    __syncthreads();

    // ---- layer 1: y1[k][o] = f[k][:6] . W1[o][:6], lrelu ----
    const float cx0 = pw[60], cx1 = pw[61], cx2 = pw[62];
    float acc[KNN];
#pragma unroll
    for (int k = 0; k < KNN; ++k) {
      const float f0 = pw[k * 3 + 0] - cx0;
      const float f1 = pw[k * 3 + 1] - cx1;
      const float f2 = pw[k * 3 + 2] - cx2;
      float y = w1r[0] * f0 + w1r[1] * f1 + w1r[2] * f2 +
                w1r[3] * cx0 + w1r[4] * cx1 + w1r[5] * cx2;
      y = y > 0.f ? y : 0.2f * y;
      acc[k] = y;
      if (STAGE == 1) { ssum += y; ssq += y * y; }
    }

    if (STAGE >= 2) {
      // stage l1 into per-wave LDS, then y2 = l1 @ W2'^T + b2'
#pragma unroll
      for (int k = 0; k < KNN; ++k) lb[k * 64 + lane] = acc[k];
      __syncthreads();
      float a2[KNN];
#pragma unroll
      for (int k = 0; k < KNN; ++k) a2[k] = bias2;
      for (int c4 = 0; c4 < 16; ++c4) {
        const float wa = w2r[c4 * 4 + 0], wb = w2r[c4 * 4 + 1];
        const float wc = w2r[c4 * 4 + 2], wd = w2r[c4 * 4 + 3];
#pragma unroll
        for (int k = 0; k < KNN; ++k) {
          const float4 l4 = lb4[k * 16 + c4];   // same-address broadcast
          a2[k] += l4.x * wa + l4.y * wb + l4.z * wc + l4.w * wd;
        }
      }
      __syncthreads();
#pragma unroll
      for (int k = 0; k < KNN; ++k) {
        float y = a2[k];
        y = y > 0.f ? y : 0.2f * y;
        acc[k] = y;
        if (STAGE == 2) { ssum += y; ssq += y * y; }
      }

      if (STAGE == 3) {
#pragma unroll
        for (int k = 0; k < KNN; ++k) lb[k * 64 + lane] = acc[k];
        __syncthreads();
        float a3[KNN];
#pragma unroll
        for (int k = 0; k < KNN; ++k) a3[k] = bias3;
        for (int c4 = 0; c4 < 16; ++c4) {
          const float wa = w3r[c4 * 4 + 0], wb = w3r[c4 * 4 + 1];
          const float wc = w3r[c4 * 4 + 2], wd = w3r[c4 * 4 + 3];
#pragma unroll
          for (int k = 0; k < KNN; ++k) {
            const float4 l4 = lb4[k * 16 + c4];
            a3[k] += l4.x * wa + l4.y * wb + l4.z * wc + l4.w * wd;
          }
        }
        float mxv = -INFINITY, mnv = INFINITY;
#pragma unroll
        for (int k = 0; k < KNN; ++k) {
          float y = a3[k];
          y = y > 0.f ? y : 0.2f * y;
          ssum += y; ssq += y * y;
          mxv = fmaxf(mxv, y); mnv = fminf(mnv, y);
        }
        mx[(size_t)p * 64 + lane] = mxv;
        mn[(size_t)p * 64 + lane] = mnv;
      }
    }
  }

  // block-level stats reduction -> one atomic per channel per block
  redS[wave * 64 + lane] = ssum;
  redQ[wave * 64 + lane] = ssq;
  __syncthreads();
  if (tid < 64) {
    const float s = redS[tid] + redS[64 + tid] + redS[128 + tid] + redS[192 + tid];
    const float q = redQ[tid] + redQ[64 + tid] + redQ[128 + tid] + redQ[192 + tid];
    atomicAdd(&sumO[tid], s);
    atomicAdd(&sqO[tid], q);
  }
}

// Fold BN(mu,var,g,b) into next weight: W'[c][o] = W[o][c]*s[c] (transposed),
// bias'[o] = sum_c W[o][c]*t[c].
__global__ void fold_kernel(const float* __restrict__ sum, const float* __restrict__ sq,
                            const float* __restrict__ g, const float* __restrict__ bt,
                            const float* __restrict__ W,
                            float* __restrict__ WfT, float* __restrict__ bf) {
  __shared__ float s[64], t[64];
  const int o = threadIdx.x;
  const float mu = sum[o] * CNT_INV;
  const float var = sq[o] * CNT_INV - mu * mu;
  const float sc = g[o] / sqrtf(var + 1e-5f);
  s[o] = sc; t[o] = bt[o] - mu * sc;
  __syncthreads();
  float acc = 0.f;
  for (int c = 0; c < 64; ++c) {
    const float w = W[o * 64 + c];
    WfT[c * 64 + o] = w * s[c];
    acc += w * t[c];
  }
  bf[o] = acc;
}

__global__ void fold3_kernel(const float* __restrict__ sum, const float* __restrict__ sq,
                             const float* __restrict__ g, const float* __restrict__ bt,
                             float* __restrict__ s3, float* __restrict__ t3) {
  const int o = threadIdx.x;
  const float mu = sum[o] * CNT_INV;
  const float var = sq[o] * CNT_INV - mu * mu;
  const float sc = g[o] / sqrtf(var + 1e-5f);
  s3[o] = sc; t3[o] = bt[o] - mu * sc;
}

// out[b][o][n] = s3[o] * (s3>=0 ? max_k : min_k) + t3[o]
__global__ __launch_bounds__(256) void final_kernel(
    const float* __restrict__ mx, const float* __restrict__ mn,
    const float* __restrict__ s3, const float* __restrict__ t3,
    float* __restrict__ out) {
  const int t = blockIdx.x * 256 + threadIdx.x;   // < 16*64*4096
  const int n = t & 4095;
  const int o = (t >> 12) & 63;
  const int b = t >> 18;
  const float sc = s3[o], tt = t3[o];
  const size_t src = ((size_t)(b * 4096 + n)) * 64 + o;
  const float v = sc >= 0.f ? mx[src] : mn[src];
  out[t] = sc * v + tt;
}

extern "C" void kernel_launch(void* const* d_in, const int* in_sizes, int n_in,
                              void* d_out, int out_size, void* d_ws, size_t ws_size,
                              hipStream_t stream) {
  const float* x  = (const float*)d_in[0];
  const float* W1 = (const float*)d_in[1];
  const float* W2 = (const float*)d_in[2];
  const float* W3 = (const float*)d_in[3];
  const float* g1 = (const float*)d_in[4];
  const float* b1 = (const float*)d_in[5];
  const float* g2 = (const float*)d_in[6];
  const float* b2 = (const float*)d_in[7];
  float* out = (float*)d_out;

  char* ws = (char*)d_ws;
  int* idx = (int*)ws;                                  // 16*4096*20*4 = 5,242,880 B
  float* stats = (float*)(ws + 5242880);                // 6*64 floats
  float* sum1 = stats,        * sq1 = stats + 64;
  float* sum2 = stats + 128,  * sq2 = stats + 192;
  float* sum3 = stats + 256,  * sq3 = stats + 320;
  float* fold = stats + 384;
  float* W2fT = fold;               // 4096
  float* b2f  = fold + 4096;        // 64
  float* W3fT = fold + 4160;        // 4096
  float* b3f  = fold + 8256;        // 64
  float* s3   = fold + 8320;        // 64
  float* t3   = fold + 8384;        // 64
  float* mx = (float*)(ws + 5242880 + 1536 + 33792);    // [B*N][64]
  float* mn = mx + (size_t)16 * 4096 * 64;

  hipMemsetAsync(stats, 0, 6 * 64 * sizeof(float), stream);

  knn_kernel<<<65536, 64, 0, stream>>>(x, idx);

  const size_t smem = 25088;
  stage_kernel<1><<<2048, 256, smem, stream>>>(x, idx, W1, nullptr, nullptr, nullptr,
                                               nullptr, sum1, sq1, nullptr, nullptr);
  fold_kernel<<<1, 64, 0, stream>>>(sum1, sq1, g1, b1, W2, W2fT, b2f);
  stage_kernel<2><<<2048, 256, smem, stream>>>(x, idx, W1, W2fT, b2f, nullptr,
                                               nullptr, sum2, sq2, nullptr, nullptr);
  fold_kernel<<<1, 64, 0, stream>>>(sum2, sq2, g1, b1, W3, W3fT, b3f);
  stage_kernel<3><<<2048, 256, smem, stream>>>(x, idx, W1, W2fT, b2f, W3fT,
                                               b3f, sum3, sq3, mx, mn);
  fold3_kernel<<<1, 64, 0, stream>>>(sum3, sq3, g2, b2, s3, t3);
  final_kernel<<<16384, 256, 0, stream>>>(mx, mn, s3, t3, out);
}

// Round 3
// 2564.673 us; speedup vs baseline: 1.4964x; 1.4964x over previous
//
#include <hip/hip_runtime.h>
#include <math.h>

// Problem constants
#define NB 16
#define NPT 4096
#define KNN 20
#define CNT_INV (1.0f / 1310720.0f)   // 1 / (B*N*K)

// ---------------------------------------------------------------------------
// KNN v2: one block (256 threads) per point.
//  Pass 1: f32 distances for 4096 candidates -> LDS; per-thread argmax over
//          its 16 candidates (m = i*256 + tid) kept in registers.
//  Select: 20 rounds of block argmax (wave butterfly + 4-entry combine);
//          after extraction only the owner thread rescans its 16 entries.
//  Re-rank: S = {20 extracted} u {d >= T - 4e-3} (margin covers f32 error vs
//          the f64 key ordering the np reference uses); recompute f64
//          distances for |S|<=64 candidates in wave 0, rank by (d64, idx),
//          write top-20. Produces the exact f64 top-k SET (order-invariant
//          downstream: BN sums + k-max).
// ---------------------------------------------------------------------------
__global__ __launch_bounds__(256) void knn_kernel(const float* __restrict__ x,
                                                  int* __restrict__ idx_out) {
  __shared__ float d[4096];
  __shared__ float wval[4];
  __shared__ int   widx[4];
  __shared__ int   exti[KNN];
  __shared__ int   slist[64];
  __shared__ int   scount;
  const int p = blockIdx.x;            // 0..65535
  const int b = p >> 12, n = p & 4095;
  const int tid = threadIdx.x;
  const int lane = tid & 63, wid = tid >> 6;
  const float* xb = x + (size_t)b * 12288;
  const float cx0 = xb[n], cx1 = xb[4096 + n], cx2 = xb[8192 + n];
  const float sqn = cx0 * cx0 + cx1 * cx1 + cx2 * cx2;

  float lmax = -INFINITY; int lidx = 0;
#pragma unroll
  for (int i = 0; i < 16; ++i) {
    const int m = i * 256 + tid;
    const float y0 = xb[m], y1 = xb[4096 + m], y2 = xb[8192 + m];
    const float dot = cx0 * y0 + cx1 * y1 + cx2 * y2;
    const float sqm = y0 * y0 + y1 * y1 + y2 * y2;
    const float nd = (2.0f * dot - sqn) - sqm;
    d[m] = nd;
    if (nd > lmax) { lmax = nd; lidx = m; }
  }
  __syncthreads();

  float T = 0.f;
  for (int r = 0; r < KNN; ++r) {
    float bv = lmax; int bi = lidx;
    for (int off = 1; off < 64; off <<= 1) {       // wave butterfly argmax
      const float ov = __shfl_xor(bv, off);
      const int   oi = __shfl_xor(bi, off);
      if (ov > bv || (ov == bv && oi < bi)) { bv = ov; bi = oi; }
    }
    if (lane == 0) { wval[wid] = bv; widx[wid] = bi; }
    __syncthreads();
    float gv = wval[0]; int gi = widx[0];
#pragma unroll
    for (int w = 1; w < 4; ++w) {
      const float ov = wval[w]; const int oi = widx[w];
      if (ov > gv || (ov == gv && oi < gi)) { gv = ov; gi = oi; }
    }
    if (tid == 0) exti[r] = gi;
    T = gv;
    if (tid == (gi & 255)) {          // owner invalidates + rescans its 16
      d[gi] = -INFINITY;
      lmax = -INFINITY; lidx = 0;
#pragma unroll
      for (int i = 0; i < 16; ++i) {
        const int m = i * 256 + tid;
        const float nd = d[m];
        if (nd > lmax) { lmax = nd; lidx = m; }
      }
    }
    __syncthreads();                  // wval/widx reusable + d[gi] settled
  }

  // Definite top-20-by-f32 first, then margin ties (extracted are -INF now).
  if (tid < KNN) slist[tid] = exti[tid];
  if (tid == 0) scount = KNN;
  __syncthreads();
  const float thr = T - 4e-3f;        // >> f32 distance computation error
#pragma unroll
  for (int i = 0; i < 16; ++i) {
    const int m = i * 256 + tid;
    if (d[m] >= thr) {
      const int pos = atomicAdd(&scount, 1);
      if (pos < 64) slist[pos] = m;
    }
  }
  __syncthreads();

  if (tid < 64) {                     // wave 0: exact f64 re-rank of S
    const int s = min(scount, 64);
    int myi = -1; double myd = -1.0e300;
    if (tid < s) {
      myi = slist[tid];
      const double c0 = (double)cx0, c1 = (double)cx1, c2 = (double)cx2;
      const double a0 = (double)xb[myi];
      const double a1 = (double)xb[4096 + myi];
      const double a2 = (double)xb[8192 + myi];
      const double dot = c0 * a0 + c1 * a1 + c2 * a2;
      const double sqm = a0 * a0 + a1 * a1 + a2 * a2;
      const double sn  = c0 * c0 + c1 * c1 + c2 * c2;
      myd = (2.0 * dot - sn) - sqm;
    }
    int rank = 0;
    for (int j = 0; j < s; ++j) {
      const double od = __shfl(myd, j);
      const int    oi = __shfl(myi, j);
      if (od > myd || (od == myd && oi < myi)) ++rank;
    }
    if (tid < s && rank < KNN) idx_out[p * KNN + rank] = myi;
  }
}

// ---------------------------------------------------------------------------
// Stage kernel: one wave per point (lane = channel), 4 waves/block, each wave
// processes exactly 8 points (grid 2048 x 256). BN folded into W2'/W3'
// (transposed [c][o] in global, rows pulled into per-lane registers).
// STAGE=1: stats of l1.  STAGE=2: recompute l1, stats of l2.
// STAGE=3: recompute l1,l2; l3 -> per-point max/min over k + stats of l3.
// ---------------------------------------------------------------------------
template <int STAGE>
__global__ __launch_bounds__(256, 2) void stage_kernel(
    const float* __restrict__ x, const int* __restrict__ nbr,
    const float* __restrict__ W1,
    const float* __restrict__ w2ft, const float* __restrict__ b2f,
    const float* __restrict__ w3ft, const float* __restrict__ b3f,
    float* __restrict__ sumO, float* __restrict__ sqO,
    float* __restrict__ mx, float* __restrict__ mn) {
  extern __shared__ char smem[];
  float* pts  = (float*)smem;                    // [4][64] (21*3 used)  1024 B
  float* W1T  = (float*)(smem + 1024);           // [6][64]              1536 B
  float* lbuf = (float*)(smem + 1024 + 1536);    // [4][20][64]         20480 B
  float* redS = (float*)(smem + 23040);          // [4][64]
  float* redQ = redS + 256;                      // [4][64]   total 25088 B

  const int tid = threadIdx.x;
  const int wave = tid >> 6, lane = tid & 63;

  for (int i = tid; i < 384; i += 256) {
    const int c = i >> 6, o = i & 63;
    W1T[i] = W1[o * 6 + c];
  }
  __syncthreads();

  float w1r[6];
#pragma unroll
  for (int c = 0; c < 6; ++c) w1r[c] = W1T[c * 64 + lane];
  float w2r[64], w3r[64];
  if (STAGE >= 2) {
#pragma unroll
    for (int c = 0; c < 64; ++c) w2r[c] = w2ft[c * 64 + lane];  // coalesced
  }
  if (STAGE == 3) {
#pragma unroll
    for (int c = 0; c < 64; ++c) w3r[c] = w3ft[c * 64 + lane];
  }
  const float bias2 = (STAGE >= 2) ? b2f[lane] : 0.f;
  const float bias3 = (STAGE == 3) ? b3f[lane] : 0.f;

  float ssum = 0.f, ssq = 0.f;
  const int wgid = blockIdx.x * 4 + wave;
  float* lb = lbuf + wave * 1280;
  float* pw = pts + wave * 64;
  const float4* lb4 = (const float4*)lb;

  for (int it = 0; it < 8; ++it) {
    const int p = wgid + it * 8192;
    const int b = p >> 12, n = p & 4095;
    const float* xb = x + (size_t)b * 12288;
    if (lane < KNN) {
      const int kk = nbr[p * KNN + lane];
      pw[lane * 3 + 0] = xb[kk];
      pw[lane * 3 + 1] = xb[4096 + kk];
      pw[lane * 3 + 2] = xb[8192 + kk];
    } else if (lane == KNN) {
      pw[60] = xb[n]; pw[61] = xb[4096 + n]; pw[62] = xb[8192 + n];
    }
    __syncthreads();

    // ---- layer 1: y1[k][o] = f[k][:6] . W1[o][:6], lrelu ----
    const float cx0 = pw[60], cx1 = pw[61], cx2 = pw[62];
    float acc[KNN];
#pragma unroll
    for (int k = 0; k < KNN; ++k) {
      const float f0 = pw[k * 3 + 0] - cx0;
      const float f1 = pw[k * 3 + 1] - cx1;
      const float f2 = pw[k * 3 + 2] - cx2;
      float y = w1r[0] * f0 + w1r[1] * f1 + w1r[2] * f2 +
                w1r[3] * cx0 + w1r[4] * cx1 + w1r[5] * cx2;
      y = y > 0.f ? y : 0.2f * y;
      acc[k] = y;
      if (STAGE == 1) { ssum += y; ssq += y * y; }
    }

    if (STAGE >= 2) {
      // stage l1 into per-wave LDS, then y2 = l1 @ W2'^T + b2'
#pragma unroll
      for (int k = 0; k < KNN; ++k) lb[k * 64 + lane] = acc[k];
      __syncthreads();
      float a2[KNN];
#pragma unroll
      for (int k = 0; k < KNN; ++k) a2[k] = bias2;
      for (int c4 = 0; c4 < 16; ++c4) {
        const float wa = w2r[c4 * 4 + 0], wb = w2r[c4 * 4 + 1];
        const float wc = w2r[c4 * 4 + 2], wd = w2r[c4 * 4 + 3];
#pragma unroll
        for (int k = 0; k < KNN; ++k) {
          const float4 l4 = lb4[k * 16 + c4];   // same-address broadcast
          a2[k] += l4.x * wa + l4.y * wb + l4.z * wc + l4.w * wd;
        }
      }
      __syncthreads();
#pragma unroll
      for (int k = 0; k < KNN; ++k) {
        float y = a2[k];
        y = y > 0.f ? y : 0.2f * y;
        acc[k] = y;
        if (STAGE == 2) { ssum += y; ssq += y * y; }
      }

      if (STAGE == 3) {
#pragma unroll
        for (int k = 0; k < KNN; ++k) lb[k * 64 + lane] = acc[k];
        __syncthreads();
        float a3[KNN];
#pragma unroll
        for (int k = 0; k < KNN; ++k) a3[k] = bias3;
        for (int c4 = 0; c4 < 16; ++c4) {
          const float wa = w3r[c4 * 4 + 0], wb = w3r[c4 * 4 + 1];
          const float wc = w3r[c4 * 4 + 2], wd = w3r[c4 * 4 + 3];
#pragma unroll
          for (int k = 0; k < KNN; ++k) {
            const float4 l4 = lb4[k * 16 + c4];
            a3[k] += l4.x * wa + l4.y * wb + l4.z * wc + l4.w * wd;
          }
        }
        float mxv = -INFINITY, mnv = INFINITY;
#pragma unroll
        for (int k = 0; k < KNN; ++k) {
          float y = a3[k];
          y = y > 0.f ? y : 0.2f * y;
          ssum += y; ssq += y * y;
          mxv = fmaxf(mxv, y); mnv = fminf(mnv, y);
        }
        mx[(size_t)p * 64 + lane] = mxv;
        mn[(size_t)p * 64 + lane] = mnv;
      }
    }
  }

  // block-level stats reduction -> one atomic per channel per block
  redS[wave * 64 + lane] = ssum;
  redQ[wave * 64 + lane] = ssq;
  __syncthreads();
  if (tid < 64) {
    const float s = redS[tid] + redS[64 + tid] + redS[128 + tid] + redS[192 + tid];
    const float q = redQ[tid] + redQ[64 + tid] + redQ[128 + tid] + redQ[192 + tid];
    atomicAdd(&sumO[tid], s);
    atomicAdd(&sqO[tid], q);
  }
}

// Fold BN(mu,var,g,b) into next weight: W'[c][o] = W[o][c]*s[c] (transposed),
// bias'[o] = sum_c W[o][c]*t[c].
__global__ void fold_kernel(const float* __restrict__ sum, const float* __restrict__ sq,
                            const float* __restrict__ g, const float* __restrict__ bt,
                            const float* __restrict__ W,
                            float* __restrict__ WfT, float* __restrict__ bf) {
  __shared__ float s[64], t[64];
  const int o = threadIdx.x;
  const float mu = sum[o] * CNT_INV;
  const float var = sq[o] * CNT_INV - mu * mu;
  const float sc = g[o] / sqrtf(var + 1e-5f);
  s[o] = sc; t[o] = bt[o] - mu * sc;
  __syncthreads();
  float acc = 0.f;
  for (int c = 0; c < 64; ++c) {
    const float w = W[o * 64 + c];
    WfT[c * 64 + o] = w * s[c];
    acc += w * t[c];
  }
  bf[o] = acc;
}

__global__ void fold3_kernel(const float* __restrict__ sum, const float* __restrict__ sq,
                             const float* __restrict__ g, const float* __restrict__ bt,
                             float* __restrict__ s3, float* __restrict__ t3) {
  const int o = threadIdx.x;
  const float mu = sum[o] * CNT_INV;
  const float var = sq[o] * CNT_INV - mu * mu;
  const float sc = g[o] / sqrtf(var + 1e-5f);
  s3[o] = sc; t3[o] = bt[o] - mu * sc;
}

// out[b][o][n] = s3[o] * (s3>=0 ? max_k : min_k) + t3[o]
__global__ __launch_bounds__(256) void final_kernel(
    const float* __restrict__ mx, const float* __restrict__ mn,
    const float* __restrict__ s3, const float* __restrict__ t3,
    float* __restrict__ out) {
  const int t = blockIdx.x * 256 + threadIdx.x;   // < 16*64*4096
  const int n = t & 4095;
  const int o = (t >> 12) & 63;
  const int b = t >> 18;
  const float sc = s3[o], tt = t3[o];
  const size_t src = ((size_t)(b * 4096 + n)) * 64 + o;
  const float v = sc >= 0.f ? mx[src] : mn[src];
  out[t] = sc * v + tt;
}

extern "C" void kernel_launch(void* const* d_in, const int* in_sizes, int n_in,
                              void* d_out, int out_size, void* d_ws, size_t ws_size,
                              hipStream_t stream) {
  const float* x  = (const float*)d_in[0];
  const float* W1 = (const float*)d_in[1];
  const float* W2 = (const float*)d_in[2];
  const float* W3 = (const float*)d_in[3];
  const float* g1 = (const float*)d_in[4];
  const float* b1 = (const float*)d_in[5];
  const float* g2 = (const float*)d_in[6];
  const float* b2 = (const float*)d_in[7];
  float* out = (float*)d_out;

  char* ws = (char*)d_ws;
  int* idx = (int*)ws;                                  // 16*4096*20*4 = 5,242,880 B
  float* stats = (float*)(ws + 5242880);                // 6*64 floats
  float* sum1 = stats,        * sq1 = stats + 64;
  float* sum2 = stats + 128,  * sq2 = stats + 192;
  float* sum3 = stats + 256,  * sq3 = stats + 320;
  float* fold = stats + 384;
  float* W2fT = fold;               // 4096
  float* b2f  = fold + 4096;        // 64
  float* W3fT = fold + 4160;        // 4096
  float* b3f  = fold + 8256;        // 64
  float* s3   = fold + 8320;        // 64
  float* t3   = fold + 8384;        // 64
  float* mx = (float*)(ws + 5242880 + 1536 + 33792);    // [B*N][64]
  float* mn = mx + (size_t)16 * 4096 * 64;

  hipMemsetAsync(stats, 0, 6 * 64 * sizeof(float), stream);

  knn_kernel<<<65536, 256, 0, stream>>>(x, idx);

  const size_t smem = 25088;
  stage_kernel<1><<<2048, 256, smem, stream>>>(x, idx, W1, nullptr, nullptr, nullptr,
                                               nullptr, sum1, sq1, nullptr, nullptr);
  fold_kernel<<<1, 64, 0, stream>>>(sum1, sq1, g1, b1, W2, W2fT, b2f);
  stage_kernel<2><<<2048, 256, smem, stream>>>(x, idx, W1, W2fT, b2f, nullptr,
                                               nullptr, sum2, sq2, nullptr, nullptr);
  fold_kernel<<<1, 64, 0, stream>>>(sum2, sq2, g1, b1, W3, W3fT, b3f);
  stage_kernel<3><<<2048, 256, smem, stream>>>(x, idx, W1, W2fT, b2f, W3fT,
                                               b3f, sum3, sq3, mx, mn);
  fold3_kernel<<<1, 64, 0, stream>>>(sum3, sq3, g2, b2, s3, t3);
  final_kernel<<<16384, 256, 0, stream>>>(mx, mn, s3, t3, out);
}

// Round 4
// 1680.548 us; speedup vs baseline: 2.2837x; 1.5261x over previous
//
#include <hip/hip_runtime.h>
#include <math.h>

// Problem constants
#define NB 16
#define NPT 4096
#define KNN 20
#define CNT_INV (1.0f / 1310720.0f)   // 1 / (B*N*K)

// ---------------------------------------------------------------------------
// KNN v3: one block (256 threads) per point. No LDS distance array, no
// extraction rounds.
//  Pass 1: f32 distances for candidates m = i*256+tid kept in 16 REGISTERS.
//  Select: bisection on threshold T over monotone count(d >= T) until
//          20 <= count <= 48 (typ. ~11 iters, one barrier each).
//  Collect: {d >= T - 4e-3} -> slist (margin >> f32 error; <= ~51 entries).
//  Re-rank: wave 0 recomputes f64 distances for slist, ranks by (d64, idx),
//          writes top-20. Produces the exact f64 top-k SET (order-invariant
//          downstream: BN sums + k-max). f64-top-20 keys satisfy
//          f32key >= d20_f32 - 2E >= T - 4e-3, so the superset is complete.
// ---------------------------------------------------------------------------
__global__ __launch_bounds__(256) void knn_kernel(const float* __restrict__ x,
                                                  int* __restrict__ idx_out) {
  __shared__ int wcnt[8];          // double-buffered per-wave counts
  __shared__ int slist[64];
  __shared__ int scount;
  const int p = blockIdx.x;            // 0..65535
  const int b = p >> 12, n = p & 4095;
  const int tid = threadIdx.x;
  const int lane = tid & 63, wid = tid >> 6;
  const float* xb = x + (size_t)b * 12288;
  const float cx0 = xb[n], cx1 = xb[4096 + n], cx2 = xb[8192 + n];
  const float sqn = cx0 * cx0 + cx1 * cx1 + cx2 * cx2;

  float dr[16];
#pragma unroll
  for (int i = 0; i < 16; ++i) {
    const int m = i * 256 + tid;
    const float y0 = xb[m], y1 = xb[4096 + m], y2 = xb[8192 + m];
    const float dot = cx0 * y0 + cx1 * y1 + cx2 * y2;
    const float sqm = y0 * y0 + y1 * y1 + y2 * y2;
    dr[i] = (2.0f * dot - sqn) - sqm;
  }

  // bisection: invariant count(>=lo) >= 20 (lo=-260 -> 4096), count(>=hi) < 20
  float lo = -260.0f, hi = 1e-3f, T = lo;
  int cnt = 4096;
  for (int it = 0; it < 28; ++it) {
    T = 0.5f * (lo + hi);
    int c = 0;
#pragma unroll
    for (int i = 0; i < 16; ++i) c += (dr[i] >= T) ? 1 : 0;
    for (int off = 1; off < 64; off <<= 1) c += __shfl_xor(c, off);
    if (lane == 0) wcnt[(it & 1) * 4 + wid] = c;
    __syncthreads();
    const int* wc = &wcnt[(it & 1) * 4];
    cnt = wc[0] + wc[1] + wc[2] + wc[3];
    if (cnt < 20) hi = T;
    else if (cnt > 48) lo = T;
    else break;
  }
  if (cnt < 20) T = lo;              // pathological-ties fallback (count>=20)

  if (tid == 0) scount = 0;
  __syncthreads();
  const float thr = T - 4e-3f;       // margin >> f32 distance error (~2e-5)
#pragma unroll
  for (int i = 0; i < 16; ++i) {
    if (dr[i] >= thr) {
      const int pos = atomicAdd(&scount, 1);
      if (pos < 64) slist[pos] = i * 256 + tid;
    }
  }
  __syncthreads();

  if (tid < 64) {                    // wave 0: exact f64 re-rank of S
    const int s = min(scount, 64);
    int myi = -1; double myd = -1.0e300;
    if (tid < s) {
      myi = slist[tid];
      const double c0 = (double)cx0, c1 = (double)cx1, c2 = (double)cx2;
      const double a0 = (double)xb[myi];
      const double a1 = (double)xb[4096 + myi];
      const double a2 = (double)xb[8192 + myi];
      const double dot = c0 * a0 + c1 * a1 + c2 * a2;
      const double sqm = a0 * a0 + a1 * a1 + a2 * a2;
      const double sn  = c0 * c0 + c1 * c1 + c2 * c2;
      myd = (2.0 * dot - sn) - sqm;
    }
    int rank = 0;
    for (int j = 0; j < s; ++j) {
      const double od = __shfl(myd, j);
      const int    oi = __shfl(myi, j);
      if (od > myd || (od == myd && oi < myi)) ++rank;
    }
    if (tid < s && rank < KNN) idx_out[p * KNN + rank] = myi;
  }
}

// ---------------------------------------------------------------------------
// Stage kernel: one wave per point (lane = channel), 4 waves/block, each wave
// processes exactly 8 points (grid 2048 x 256). BN folded into W2'/W3'
// (transposed [c][o] in global, rows pulled into per-lane registers).
// STAGE=1: stats of l1.  STAGE=2: recompute l1, stats of l2.
// STAGE=3: recompute l1,l2; l3 -> per-point max/min over k + stats of l3.
// ---------------------------------------------------------------------------
template <int STAGE>
__global__ __launch_bounds__(256, 2) void stage_kernel(
    const float* __restrict__ x, const int* __restrict__ nbr,
    const float* __restrict__ W1,
    const float* __restrict__ w2ft, const float* __restrict__ b2f,
    const float* __restrict__ w3ft, const float* __restrict__ b3f,
    float* __restrict__ sumO, float* __restrict__ sqO,
    float* __restrict__ mx, float* __restrict__ mn) {
  extern __shared__ char smem[];
  float* pts  = (float*)smem;                    // [4][64] (21*3 used)  1024 B
  float* W1T  = (float*)(smem + 1024);           // [6][64]              1536 B
  float* lbuf = (float*)(smem + 1024 + 1536);    // [4][20][64]         20480 B
  float* redS = (float*)(smem + 23040);          // [4][64]
  float* redQ = redS + 256;                      // [4][64]   total 25088 B

  const int tid = threadIdx.x;
  const int wave = tid >> 6, lane = tid & 63;

  for (int i = tid; i < 384; i += 256) {
    const int c = i >> 6, o = i & 63;
    W1T[i] = W1[o * 6 + c];
  }
  __syncthreads();

  float w1r[6];
#pragma unroll
  for (int c = 0; c < 6; ++c) w1r[c] = W1T[c * 64 + lane];
  float w2r[64], w3r[64];
  if (STAGE >= 2) {
#pragma unroll
    for (int c = 0; c < 64; ++c) w2r[c] = w2ft[c * 64 + lane];  // coalesced
  }
  if (STAGE == 3) {
#pragma unroll
    for (int c = 0; c < 64; ++c) w3r[c] = w3ft[c * 64 + lane];
  }
  const float bias2 = (STAGE >= 2) ? b2f[lane] : 0.f;
  const float bias3 = (STAGE == 3) ? b3f[lane] : 0.f;

  float ssum = 0.f, ssq = 0.f;
  const int wgid = blockIdx.x * 4 + wave;
  float* lb = lbuf + wave * 1280;
  float* pw = pts + wave * 64;
  const float4* lb4 = (const float4*)lb;

  for (int it = 0; it < 8; ++it) {
    const int p = wgid + it * 8192;
    const int b = p >> 12, n = p & 4095;
    const float* xb = x + (size_t)b * 12288;
    if (lane < KNN) {
      const int kk = nbr[p * KNN + lane];
      pw[lane * 3 + 0] = xb[kk];
      pw[lane * 3 + 1] = xb[4096 + kk];
      pw[lane * 3 + 2] = xb[8192 + kk];
    } else if (lane == KNN) {
      pw[60] = xb[n]; pw[61] = xb[4096 + n]; pw[62] = xb[8192 + n];
    }
    __syncthreads();

    // ---- layer 1: y1[k][o] = f[k][:6] . W1[o][:6], lrelu ----
    const float cx0 = pw[60], cx1 = pw[61], cx2 = pw[62];
    float acc[KNN];
#pragma unroll
    for (int k = 0; k < KNN; ++k) {
      const float f0 = pw[k * 3 + 0] - cx0;
      const float f1 = pw[k * 3 + 1] - cx1;
      const float f2 = pw[k * 3 + 2] - cx2;
      float y = w1r[0] * f0 + w1r[1] * f1 + w1r[2] * f2 +
                w1r[3] * cx0 + w1r[4] * cx1 + w1r[5] * cx2;
      y = y > 0.f ? y : 0.2f * y;
      acc[k] = y;
      if (STAGE == 1) { ssum += y; ssq += y * y; }
    }

    if (STAGE >= 2) {
      // stage l1 into per-wave LDS, then y2 = l1 @ W2'^T + b2'
#pragma unroll
      for (int k = 0; k < KNN; ++k) lb[k * 64 + lane] = acc[k];
      __syncthreads();
      float a2[KNN];
#pragma unroll
      for (int k = 0; k < KNN; ++k) a2[k] = bias2;
      for (int c4 = 0; c4 < 16; ++c4) {
        const float wa = w2r[c4 * 4 + 0], wb = w2r[c4 * 4 + 1];
        const float wc = w2r[c4 * 4 + 2], wd = w2r[c4 * 4 + 3];
#pragma unroll
        for (int k = 0; k < KNN; ++k) {
          const float4 l4 = lb4[k * 16 + c4];   // same-address broadcast
          a2[k] += l4.x * wa + l4.y * wb + l4.z * wc + l4.w * wd;
        }
      }
      __syncthreads();
#pragma unroll
      for (int k = 0; k < KNN; ++k) {
        float y = a2[k];
        y = y > 0.f ? y : 0.2f * y;
        acc[k] = y;
        if (STAGE == 2) { ssum += y; ssq += y * y; }
      }

      if (STAGE == 3) {
#pragma unroll
        for (int k = 0; k < KNN; ++k) lb[k * 64 + lane] = acc[k];
        __syncthreads();
        float a3[KNN];
#pragma unroll
        for (int k = 0; k < KNN; ++k) a3[k] = bias3;
        for (int c4 = 0; c4 < 16; ++c4) {
          const float wa = w3r[c4 * 4 + 0], wb = w3r[c4 * 4 + 1];
          const float wc = w3r[c4 * 4 + 2], wd = w3r[c4 * 4 + 3];
#pragma unroll
          for (int k = 0; k < KNN; ++k) {
            const float4 l4 = lb4[k * 16 + c4];
            a3[k] += l4.x * wa + l4.y * wb + l4.z * wc + l4.w * wd;
          }
        }
        float mxv = -INFINITY, mnv = INFINITY;
#pragma unroll
        for (int k = 0; k < KNN; ++k) {
          float y = a3[k];
          y = y > 0.f ? y : 0.2f * y;
          ssum += y; ssq += y * y;
          mxv = fmaxf(mxv, y); mnv = fminf(mnv, y);
        }
        mx[(size_t)p * 64 + lane] = mxv;
        mn[(size_t)p * 64 + lane] = mnv;
      }
    }
  }

  // block-level stats reduction -> one atomic per channel per block
  redS[wave * 64 + lane] = ssum;
  redQ[wave * 64 + lane] = ssq;
  __syncthreads();
  if (tid < 64) {
    const float s = redS[tid] + redS[64 + tid] + redS[128 + tid] + redS[192 + tid];
    const float q = redQ[tid] + redQ[64 + tid] + redQ[128 + tid] + redQ[192 + tid];
    atomicAdd(&sumO[tid], s);
    atomicAdd(&sqO[tid], q);
  }
}

// Fold BN(mu,var,g,b) into next weight: W'[c][o] = W[o][c]*s[c] (transposed),
// bias'[o] = sum_c W[o][c]*t[c].
__global__ void fold_kernel(const float* __restrict__ sum, const float* __restrict__ sq,
                            const float* __restrict__ g, const float* __restrict__ bt,
                            const float* __restrict__ W,
                            float* __restrict__ WfT, float* __restrict__ bf) {
  __shared__ float s[64], t[64];
  const int o = threadIdx.x;
  const float mu = sum[o] * CNT_INV;
  const float var = sq[o] * CNT_INV - mu * mu;
  const float sc = g[o] / sqrtf(var + 1e-5f);
  s[o] = sc; t[o] = bt[o] - mu * sc;
  __syncthreads();
  float acc = 0.f;
  for (int c = 0; c < 64; ++c) {
    const float w = W[o * 64 + c];
    WfT[c * 64 + o] = w * s[c];
    acc += w * t[c];
  }
  bf[o] = acc;
}

__global__ void fold3_kernel(const float* __restrict__ sum, const float* __restrict__ sq,
                             const float* __restrict__ g, const float* __restrict__ bt,
                             float* __restrict__ s3, float* __restrict__ t3) {
  const int o = threadIdx.x;
  const float mu = sum[o] * CNT_INV;
  const float var = sq[o] * CNT_INV - mu * mu;
  const float sc = g[o] / sqrtf(var + 1e-5f);
  s3[o] = sc; t3[o] = bt[o] - mu * sc;
}

// out[b][o][n] = s3[o] * (s3>=0 ? max_k : min_k) + t3[o]
__global__ __launch_bounds__(256) void final_kernel(
    const float* __restrict__ mx, const float* __restrict__ mn,
    const float* __restrict__ s3, const float* __restrict__ t3,
    float* __restrict__ out) {
  const int t = blockIdx.x * 256 + threadIdx.x;   // < 16*64*4096
  const int n = t & 4095;
  const int o = (t >> 12) & 63;
  const int b = t >> 18;
  const float sc = s3[o], tt = t3[o];
  const size_t src = ((size_t)(b * 4096 + n)) * 64 + o;
  const float v = sc >= 0.f ? mx[src] : mn[src];
  out[t] = sc * v + tt;
}

extern "C" void kernel_launch(void* const* d_in, const int* in_sizes, int n_in,
                              void* d_out, int out_size, void* d_ws, size_t ws_size,
                              hipStream_t stream) {
  const float* x  = (const float*)d_in[0];
  const float* W1 = (const float*)d_in[1];
  const float* W2 = (const float*)d_in[2];
  const float* W3 = (const float*)d_in[3];
  const float* g1 = (const float*)d_in[4];
  const float* b1 = (const float*)d_in[5];
  const float* g2 = (const float*)d_in[6];
  const float* b2 = (const float*)d_in[7];
  float* out = (float*)d_out;

  char* ws = (char*)d_ws;
  int* idx = (int*)ws;                                  // 16*4096*20*4 = 5,242,880 B
  float* stats = (float*)(ws + 5242880);                // 6*64 floats
  float* sum1 = stats,        * sq1 = stats + 64;
  float* sum2 = stats + 128,  * sq2 = stats + 192;
  float* sum3 = stats + 256,  * sq3 = stats + 320;
  float* fold = stats + 384;
  float* W2fT = fold;               // 4096
  float* b2f  = fold + 4096;        // 64
  float* W3fT = fold + 4160;        // 4096
  float* b3f  = fold + 8256;        // 64
  float* s3   = fold + 8320;        // 64
  float* t3   = fold + 8384;        // 64
  float* mx = (float*)(ws + 5242880 + 1536 + 33792);    // [B*N][64]
  float* mn = mx + (size_t)16 * 4096 * 64;

  hipMemsetAsync(stats, 0, 6 * 64 * sizeof(float), stream);

  knn_kernel<<<65536, 256, 0, stream>>>(x, idx);

  const size_t smem = 25088;
  stage_kernel<1><<<2048, 256, smem, stream>>>(x, idx, W1, nullptr, nullptr, nullptr,
                                               nullptr, sum1, sq1, nullptr, nullptr);
  fold_kernel<<<1, 64, 0, stream>>>(sum1, sq1, g1, b1, W2, W2fT, b2f);
  stage_kernel<2><<<2048, 256, smem, stream>>>(x, idx, W1, W2fT, b2f, nullptr,
                                               nullptr, sum2, sq2, nullptr, nullptr);
  fold_kernel<<<1, 64, 0, stream>>>(sum2, sq2, g1, b1, W3, W3fT, b3f);
  stage_kernel<3><<<2048, 256, smem, stream>>>(x, idx, W1, W2fT, b2f, W3fT,
                                               b3f, sum3, sq3, mx, mn);
  fold3_kernel<<<1, 64, 0, stream>>>(sum3, sq3, g2, b2, s3, t3);
  final_kernel<<<16384, 256, 0, stream>>>(mx, mn, s3, t3, out);
}

// Round 5
// 824.087 us; speedup vs baseline: 4.6571x; 2.0393x over previous
//
#include <hip/hip_runtime.h>
#include <math.h>

#define KNN 20
#define CNT_INV (1.0f / 1310720.0f)   // 1 / (B*N*K)

typedef short bf16x8 __attribute__((ext_vector_type(8)));   // 8 bf16 in 4 VGPRs
typedef float f32x4  __attribute__((ext_vector_type(4)));

__device__ __forceinline__ short f2bf(float f) {            // RNE f32->bf16
  unsigned u = __builtin_bit_cast(unsigned, f);
  u += 0x7FFFu + ((u >> 16) & 1u);
  return (short)(u >> 16);
}
__device__ __forceinline__ float lrelu(float y) { return y > 0.f ? y : 0.2f * y; }

// ---------------------------------------------------------------------------
// KNN + layer-1 BN stats fused. One block (256 threads) per point.
// Distance pass in f32 registers -> count-threshold bisection -> margin
// collect -> exact f64 re-rank of <=64 candidates (matches np f64 top-k SET;
// downstream is order-invariant). Then all 256 threads compute l1 stats for
// this point (1280 values) and bucket-atomicAdd (256 buckets kills contention).
// ---------------------------------------------------------------------------
__global__ __launch_bounds__(256) void knn_kernel(const float* __restrict__ x,
                                                  int* __restrict__ idx_out,
                                                  const float* __restrict__ W1,
                                                  float* __restrict__ s1buf) {
  __shared__ int   wcnt[8];
  __shared__ int   slist[64];
  __shared__ int   scount;
  __shared__ int   eidx[KNN];
  __shared__ float W1s[384];
  __shared__ float redS[256], redQ[256];
  const int p = blockIdx.x;
  const int b = p >> 12, n = p & 4095;
  const int tid = threadIdx.x;
  const int lane = tid & 63, wid = tid >> 6;
  const float* xb = x + (size_t)b * 12288;
  const float cx0 = xb[n], cx1 = xb[4096 + n], cx2 = xb[8192 + n];
  const float sqn = cx0 * cx0 + cx1 * cx1 + cx2 * cx2;

  for (int i = tid; i < 384; i += 256) W1s[i] = W1[(i & 63) * 6 + (i >> 6)];

  float dr[16];
#pragma unroll
  for (int i = 0; i < 16; ++i) {
    const int m = i * 256 + tid;
    const float y0 = xb[m], y1 = xb[4096 + m], y2 = xb[8192 + m];
    const float dot = cx0 * y0 + cx1 * y1 + cx2 * y2;
    const float sqm = y0 * y0 + y1 * y1 + y2 * y2;
    dr[i] = (2.0f * dot - sqn) - sqm;
  }

  // bisection: invariant count(>=lo) >= 20, hi above everything
  float lo = -260.0f, hi = 1e-3f, T = lo;
  int cnt = 4096;
  for (int it = 0; it < 28; ++it) {
    T = 0.5f * (lo + hi);
    int c = 0;
#pragma unroll
    for (int i = 0; i < 16; ++i) c += (dr[i] >= T) ? 1 : 0;
    for (int off = 1; off < 64; off <<= 1) c += __shfl_xor(c, off);
    if (lane == 0) wcnt[(it & 1) * 4 + wid] = c;
    __syncthreads();
    const int* wc = &wcnt[(it & 1) * 4];
    cnt = wc[0] + wc[1] + wc[2] + wc[3];
    if (cnt < 20) hi = T;
    else if (cnt > 48) lo = T;
    else break;
  }
  if (cnt < 20) T = lo;              // pathological-ties fallback (count>=20)

  if (tid == 0) scount = 0;
  __syncthreads();
  const float thr = T - 4e-3f;       // margin >> f32 distance error (~2e-5)
#pragma unroll
  for (int i = 0; i < 16; ++i) {
    if (dr[i] >= thr) {
      const int pos = atomicAdd(&scount, 1);
      if (pos < 64) slist[pos] = i * 256 + tid;
    }
  }
  __syncthreads();

  if (tid < 64) {                    // wave 0: exact f64 re-rank of S
    const int s = min(scount, 64);
    int myi = -1; double myd = -1.0e300;
    if (tid < s) {
      myi = slist[tid];
      const double c0 = (double)cx0, c1 = (double)cx1, c2 = (double)cx2;
      const double a0 = (double)xb[myi];
      const double a1 = (double)xb[4096 + myi];
      const double a2 = (double)xb[8192 + myi];
      const double dot = c0 * a0 + c1 * a1 + c2 * a2;
      const double sqm = a0 * a0 + a1 * a1 + a2 * a2;
      const double sn  = c0 * c0 + c1 * c1 + c2 * c2;
      myd = (2.0 * dot - sn) - sqm;
    }
    int rank = 0;
    for (int j = 0; j < s; ++j) {
      const double od = __shfl(myd, j);
      const int    oi = __shfl(myi, j);
      if (od > myd || (od == myd && oi < myi)) ++rank;
    }
    if (tid < s && rank < KNN) { idx_out[p * KNN + rank] = myi; eidx[rank] = myi; }
  }
  __syncthreads();

  // ---- fused layer-1 stats: thread -> channel o = tid&63, k = tid>>6 + 4t
  const int o = tid & 63, kb = tid >> 6;
  const float w0 = W1s[o],       w1 = W1s[64 + o],  w2 = W1s[128 + o];
  const float w3 = W1s[192 + o], w4 = W1s[256 + o], w5 = W1s[320 + o];
  float sm = 0.f, sq = 0.f;
#pragma unroll
  for (int t = 0; t < 5; ++t) {
    const int kk = eidx[kb + 4 * t];
    const float y0 = xb[kk], y1 = xb[4096 + kk], y2 = xb[8192 + kk];
    float y = w0 * (y0 - cx0) + w1 * (y1 - cx1) + w2 * (y2 - cx2) +
              w3 * cx0 + w4 * cx1 + w5 * cx2;
    y = lrelu(y);
    sm += y; sq += y * y;
  }
  redS[tid] = sm; redQ[tid] = sq;
  __syncthreads();
  if (tid < 64) {
    const float s  = redS[tid] + redS[64 + tid] + redS[128 + tid] + redS[192 + tid];
    const float qq = redQ[tid] + redQ[64 + tid] + redQ[128 + tid] + redQ[192 + tid];
    float* bk = s1buf + (size_t)(blockIdx.x & 255) * 128;
    atomicAdd(&bk[tid], s);
    atomicAdd(&bk[64 + tid], qq);
  }
}

// ---------------------------------------------------------------------------
// Stage kernel (MFMA): one wave per point, 4 waves/block, 8 points/wave.
// Per-wave LDS A-buffer in 16x16x32-bf16 A-fragment layout (tiles [mt][kt],
// lane-major 16B units). Weights W2'/W3' live in registers as B-fragments.
// l1 in VALU (lane=channel) -> bf16 A-stage -> l2 = 16 MFMAs -> (stage2:
// stats) | (stage3: restage -> l3 = 16 MFMAs -> stats + per-point max/min).
// All LDS buffers are wave-private: DS ops of a wave complete in order, so
// no block barriers are needed inside the point loop.
// ---------------------------------------------------------------------------
template <int STAGE>
__global__ __launch_bounds__(256, 2) void stage_kernel(
    const float* __restrict__ x, const int* __restrict__ nbr,
    const float* __restrict__ W1,
    const float* __restrict__ w2ft, const float* __restrict__ b2f,
    const float* __restrict__ w3ft, const float* __restrict__ b3f,
    float* __restrict__ sumO, float* __restrict__ sqO,
    float* __restrict__ mx, float* __restrict__ mn) {
  __shared__ float pts[4][96];          // stride-4 per k, center at 80..82
  __shared__ float W1T[384];
  __shared__ short abuf[4][2048];       // [mt*2+kt][lane][8] bf16
  __shared__ float redS[256], redQ[256];

  const int tid = threadIdx.x, wave = tid >> 6, lane = tid & 63;
  const int q = lane >> 4, cc = lane & 15;

  for (int i = tid; i < 384; i += 256) W1T[i] = W1[(i & 63) * 6 + (i >> 6)];
  __syncthreads();

  float w1r[6];
#pragma unroll
  for (int c = 0; c < 6; ++c) w1r[c] = W1T[c * 64 + lane];

  // B-fragments: lane holds B[k=kt*32+q*8+j][n=nt*16+cc]
  bf16x8 w2f[2][4];
#pragma unroll
  for (int kt = 0; kt < 2; ++kt)
#pragma unroll
    for (int nt = 0; nt < 4; ++nt)
#pragma unroll
      for (int j = 0; j < 8; ++j)
        w2f[kt][nt][j] = f2bf(w2ft[(kt * 32 + q * 8 + j) * 64 + nt * 16 + cc]);
  float bias2v[4];
#pragma unroll
  for (int nt = 0; nt < 4; ++nt) bias2v[nt] = b2f[nt * 16 + cc];

  bf16x8 w3f[2][4];
  float bias3v[4];
  if (STAGE == 3) {
#pragma unroll
    for (int kt = 0; kt < 2; ++kt)
#pragma unroll
      for (int nt = 0; nt < 4; ++nt)
#pragma unroll
        for (int j = 0; j < 8; ++j)
          w3f[kt][nt][j] = f2bf(w3ft[(kt * 32 + q * 8 + j) * 64 + nt * 16 + cc]);
#pragma unroll
    for (int nt = 0; nt < 4; ++nt) bias3v[nt] = b3f[nt * 16 + cc];
  }

  // l1 producer indices (this lane = channel c0 = lane)
  const int kt1 = lane >> 5, q1 = (lane & 31) >> 3, j1 = lane & 7;
  short* ab = abuf[wave];
  const bf16x8* ab8 = (const bf16x8*)ab;
  float* pw = pts[wave];

  float s_s[4] = {0.f, 0.f, 0.f, 0.f}, s_q[4] = {0.f, 0.f, 0.f, 0.f};
  const int wgid = blockIdx.x * 4 + wave;

  for (int it = 0; it < 8; ++it) {
    const int p = wgid + it * 8192;
    const int b = p >> 12, n = p & 4095;
    const float* xb = x + (size_t)b * 12288;
    if (lane < KNN) {
      const int kk = nbr[p * KNN + lane];
      pw[lane * 4 + 0] = xb[kk];
      pw[lane * 4 + 1] = xb[4096 + kk];
      pw[lane * 4 + 2] = xb[8192 + kk];
    } else if (lane == KNN) {
      pw[80] = xb[n]; pw[81] = xb[4096 + n]; pw[82] = xb[8192 + n];
    }
    // wave-private LDS: in-order DS pipe makes these visible to the wave
    const float cx0 = pw[80], cx1 = pw[81], cx2 = pw[82];

    // ---- l1 (VALU, lane = channel) + bf16 A-stage ----
#pragma unroll
    for (int k = 0; k < KNN; ++k) {
      const float4 pk = *(const float4*)&pw[k * 4];
      const float f0 = pk.x - cx0, f1 = pk.y - cx1, f2 = pk.z - cx2;
      float y = w1r[0] * f0 + w1r[1] * f1 + w1r[2] * f2 +
                w1r[3] * cx0 + w1r[4] * cx1 + w1r[5] * cx2;
      y = lrelu(y);
      ab[(((k >> 4) * 2 + kt1) * 64 + q1 * 16 + (k & 15)) * 8 + j1] = f2bf(y);
    }

    // ---- l2: 16 MFMAs ----
    f32x4 acc2[2][4];
#pragma unroll
    for (int mt = 0; mt < 2; ++mt)
#pragma unroll
      for (int nt = 0; nt < 4; ++nt)
        acc2[mt][nt] = f32x4{bias2v[nt], bias2v[nt], bias2v[nt], bias2v[nt]};
#pragma unroll
    for (int kt = 0; kt < 2; ++kt) {
      const bf16x8 a0 = ab8[(0 * 2 + kt) * 64 + lane];
      const bf16x8 a1 = ab8[(1 * 2 + kt) * 64 + lane];
#pragma unroll
      for (int nt = 0; nt < 4; ++nt) {
        acc2[0][nt] = __builtin_amdgcn_mfma_f32_16x16x32_bf16(a0, w2f[kt][nt], acc2[0][nt], 0, 0, 0);
        acc2[1][nt] = __builtin_amdgcn_mfma_f32_16x16x32_bf16(a1, w2f[kt][nt], acc2[1][nt], 0, 0, 0);
      }
    }

    if (STAGE == 2) {
      // stats of l2 (mask rows k>=20: mt==1 valid only in quad 0)
#pragma unroll
      for (int mt = 0; mt < 2; ++mt)
#pragma unroll
        for (int nt = 0; nt < 4; ++nt)
#pragma unroll
          for (int r = 0; r < 4; ++r) {
            if (mt == 1 && q != 0) continue;
            const float y = lrelu(acc2[mt][nt][r]);
            s_s[nt] += y; s_q[nt] += y * y;
          }
    } else {
      // re-stage l2 -> A-layout for l3 (row k = mt*16+q*4+r, col o = nt*16+cc)
#pragma unroll
      for (int mt = 0; mt < 2; ++mt)
#pragma unroll
        for (int nt = 0; nt < 4; ++nt) {
          const int kt3 = nt >> 1;
          const int q3 = (nt & 1) * 2 + (cc >> 3);
          const int j3 = cc & 7;
#pragma unroll
          for (int r = 0; r < 4; ++r) {
            if (mt == 1 && q != 0) continue;
            const float y = lrelu(acc2[mt][nt][r]);
            ab[((mt * 2 + kt3) * 64 + q3 * 16 + q * 4 + r) * 8 + j3] = f2bf(y);
          }
        }

      // ---- l3: 16 MFMAs ----
      f32x4 acc3[2][4];
#pragma unroll
      for (int mt = 0; mt < 2; ++mt)
#pragma unroll
        for (int nt = 0; nt < 4; ++nt)
          acc3[mt][nt] = f32x4{bias3v[nt], bias3v[nt], bias3v[nt], bias3v[nt]};
#pragma unroll
      for (int kt = 0; kt < 2; ++kt) {
        const bf16x8 a0 = ab8[(0 * 2 + kt) * 64 + lane];
        const bf16x8 a1 = ab8[(1 * 2 + kt) * 64 + lane];
#pragma unroll
        for (int nt = 0; nt < 4; ++nt) {
          acc3[0][nt] = __builtin_amdgcn_mfma_f32_16x16x32_bf16(a0, w3f[kt][nt], acc3[0][nt], 0, 0, 0);
          acc3[1][nt] = __builtin_amdgcn_mfma_f32_16x16x32_bf16(a1, w3f[kt][nt], acc3[1][nt], 0, 0, 0);
        }
      }

      // epilogue: lrelu + stats + per-point max/min over k
      float vmx[4], vmn[4];
#pragma unroll
      for (int nt = 0; nt < 4; ++nt) { vmx[nt] = -INFINITY; vmn[nt] = INFINITY; }
#pragma unroll
      for (int mt = 0; mt < 2; ++mt)
#pragma unroll
        for (int nt = 0; nt < 4; ++nt)
#pragma unroll
          for (int r = 0; r < 4; ++r) {
            if (mt == 1 && q != 0) continue;
            const float y = lrelu(acc3[mt][nt][r]);
            s_s[nt] += y; s_q[nt] += y * y;
            vmx[nt] = fmaxf(vmx[nt], y); vmn[nt] = fminf(vmn[nt], y);
          }
#pragma unroll
      for (int nt = 0; nt < 4; ++nt) {
        vmx[nt] = fmaxf(vmx[nt], __shfl_xor(vmx[nt], 16));
        vmx[nt] = fmaxf(vmx[nt], __shfl_xor(vmx[nt], 32));
        vmn[nt] = fminf(vmn[nt], __shfl_xor(vmn[nt], 16));
        vmn[nt] = fminf(vmn[nt], __shfl_xor(vmn[nt], 32));
      }
      const float omx = q == 0 ? vmx[0] : q == 1 ? vmx[1] : q == 2 ? vmx[2] : vmx[3];
      const float omn = q == 0 ? vmn[0] : q == 1 ? vmn[1] : q == 2 ? vmn[2] : vmn[3];
      mx[(size_t)p * 64 + lane] = omx;   // lane L holds column o = L after select
      mn[(size_t)p * 64 + lane] = omn;
    }
  }

  // stats: butterfly across quads, select own nt, then block reduce
#pragma unroll
  for (int nt = 0; nt < 4; ++nt) {
    s_s[nt] += __shfl_xor(s_s[nt], 16); s_s[nt] += __shfl_xor(s_s[nt], 32);
    s_q[nt] += __shfl_xor(s_q[nt], 16); s_q[nt] += __shfl_xor(s_q[nt], 32);
  }
  const float ms = q == 0 ? s_s[0] : q == 1 ? s_s[1] : q == 2 ? s_s[2] : s_s[3];
  const float mq = q == 0 ? s_q[0] : q == 1 ? s_q[1] : q == 2 ? s_q[2] : s_q[3];
  redS[tid] = ms; redQ[tid] = mq;
  __syncthreads();
  if (tid < 64) {
    const float s  = redS[tid] + redS[64 + tid] + redS[128 + tid] + redS[192 + tid];
    const float qq = redQ[tid] + redQ[64 + tid] + redQ[128 + tid] + redQ[192 + tid];
    atomicAdd(&sumO[tid], s);
    atomicAdd(&sqO[tid], qq);
  }
}

// fold1: sum 256 stat buckets, then fold BN into W2 (transposed + bias)
__global__ void fold1_kernel(const float* __restrict__ s1buf,
                             const float* __restrict__ g, const float* __restrict__ bt,
                             const float* __restrict__ W,
                             float* __restrict__ WfT, float* __restrict__ bf) {
  __shared__ float s[64], t[64];
  const int o = threadIdx.x;
  float sm = 0.f, qq = 0.f;
  for (int k = 0; k < 256; ++k) { sm += s1buf[k * 128 + o]; qq += s1buf[k * 128 + 64 + o]; }
  const float mu = sm * CNT_INV;
  const float var = qq * CNT_INV - mu * mu;
  const float sc = g[o] / sqrtf(var + 1e-5f);
  s[o] = sc; t[o] = bt[o] - mu * sc;
  __syncthreads();
  float acc = 0.f;
  for (int c = 0; c < 64; ++c) {
    const float w = W[o * 64 + c];
    WfT[c * 64 + o] = w * s[c];
    acc += w * t[c];
  }
  bf[o] = acc;
}

// fold from direct sum/sq
__global__ void fold_kernel(const float* __restrict__ sum, const float* __restrict__ sq,
                            const float* __restrict__ g, const float* __restrict__ bt,
                            const float* __restrict__ W,
                            float* __restrict__ WfT, float* __restrict__ bf) {
  __shared__ float s[64], t[64];
  const int o = threadIdx.x;
  const float mu = sum[o] * CNT_INV;
  const float var = sq[o] * CNT_INV - mu * mu;
  const float sc = g[o] / sqrtf(var + 1e-5f);
  s[o] = sc; t[o] = bt[o] - mu * sc;
  __syncthreads();
  float acc = 0.f;
  for (int c = 0; c < 64; ++c) {
    const float w = W[o * 64 + c];
    WfT[c * 64 + o] = w * s[c];
    acc += w * t[c];
  }
  bf[o] = acc;
}

__global__ void fold3_kernel(const float* __restrict__ sum, const float* __restrict__ sq,
                             const float* __restrict__ g, const float* __restrict__ bt,
                             float* __restrict__ s3, float* __restrict__ t3) {
  const int o = threadIdx.x;
  const float mu = sum[o] * CNT_INV;
  const float var = sq[o] * CNT_INV - mu * mu;
  const float sc = g[o] / sqrtf(var + 1e-5f);
  s3[o] = sc; t3[o] = bt[o] - mu * sc;
}

// out[b][o][n] = s3[o] * (s3>=0 ? max_k : min_k) + t3[o]
__global__ __launch_bounds__(256) void final_kernel(
    const float* __restrict__ mx, const float* __restrict__ mn,
    const float* __restrict__ s3, const float* __restrict__ t3,
    float* __restrict__ out) {
  const int t = blockIdx.x * 256 + threadIdx.x;
  const int n = t & 4095;
  const int o = (t >> 12) & 63;
  const int b = t >> 18;
  const float sc = s3[o], tt = t3[o];
  const size_t src = ((size_t)(b * 4096 + n)) * 64 + o;
  const float v = sc >= 0.f ? mx[src] : mn[src];
  out[t] = sc * v + tt;
}

extern "C" void kernel_launch(void* const* d_in, const int* in_sizes, int n_in,
                              void* d_out, int out_size, void* d_ws, size_t ws_size,
                              hipStream_t stream) {
  const float* x  = (const float*)d_in[0];
  const float* W1 = (const float*)d_in[1];
  const float* W2 = (const float*)d_in[2];
  const float* W3 = (const float*)d_in[3];
  const float* g1 = (const float*)d_in[4];
  const float* b1 = (const float*)d_in[5];
  const float* g2 = (const float*)d_in[6];
  const float* b2 = (const float*)d_in[7];
  float* out = (float*)d_out;

  char* ws = (char*)d_ws;
  int* idx = (int*)ws;                              // 5,242,880 B
  float* F = (float*)(ws + 5242880);
  float* sum2 = F + 0,   * sq2 = F + 64;
  float* sum3 = F + 128, * sq3 = F + 192;
  float* s1buf = F + 256;                           // 256 buckets x 128
  float* W2fT = F + 33024;                          // 4096
  float* b2f  = F + 37120;                          // 64
  float* W3fT = F + 37184;                          // 4096
  float* b3f  = F + 41280;                          // 64
  float* s3   = F + 41344;
  float* t3   = F + 41408;
  float* mx = (float*)(ws + 5408768);               // [B*N][64]
  float* mn = mx + (size_t)16 * 4096 * 64;

  hipMemsetAsync(F, 0, 33024 * sizeof(float), stream);   // stats + buckets

  knn_kernel<<<65536, 256, 0, stream>>>(x, idx, W1, s1buf);
  fold1_kernel<<<1, 64, 0, stream>>>(s1buf, g1, b1, W2, W2fT, b2f);
  stage_kernel<2><<<2048, 256, 0, stream>>>(x, idx, W1, W2fT, b2f, nullptr,
                                            nullptr, sum2, sq2, nullptr, nullptr);
  fold_kernel<<<1, 64, 0, stream>>>(sum2, sq2, g1, b1, W3, W3fT, b3f);
  stage_kernel<3><<<2048, 256, 0, stream>>>(x, idx, W1, W2fT, b2f, W3fT,
                                            b3f, sum3, sq3, mx, mn);
  fold3_kernel<<<1, 64, 0, stream>>>(sum3, sq3, g2, b2, s3, t3);
  final_kernel<<<16384, 256, 0, stream>>>(mx, mn, s3, t3, out);
}